// Round 23
// baseline (106.959 us; speedup 1.0000x reference)
//
#include <hip/hip_runtime.h>
#include <hip/hip_bf16.h>

#define BATCH 256
#define L 1024
#define C 16
#define POOL 512
#define PCOLS 5632
#define FDIM 90112        // 11 levels * 8192
#define H1 128
#define H2 64

#define KS 256            // split-K factor for fc1 mfma GEMM
#define KCHUNK (FDIM / KS)   // 352

#define SROW 24                    // bf16 per state row (48B, 16B-aligned)
#define SBUF (1025 * SROW)         // +1 zero row
#define TREE_LDS_BYTES (2 * SBUF * 2)   // 98400 B

#define TROW 520                   // transpose-stage LDS row stride (shorts)

typedef float f32x4 __attribute__((ext_vector_type(4)));
typedef short bf16x8 __attribute__((ext_vector_type(8)));
typedef unsigned long long u64;

__device__ __forceinline__ unsigned short f2b(float f) {
    union { __hip_bfloat16 h; unsigned short u; } cv;
    cv.h = __float2bfloat16(f);          // RNE, hardware v_cvt
    return cv.u;
}
__device__ __forceinline__ unsigned int pk(float lo, float hi) {
    return (unsigned int)f2b(lo) | ((unsigned int)f2b(hi) << 16);
}

// ---------------- Kernel 1: tree via MFMA + fused w1 convert/permute ----------------
// pooled layout: f_new = level*8192 + pos2*16 + c   (w1 permuted to match)
// ti-loop fully unrolled (4 independent ds_read->MFMA chains); pooled stores
// DEFERRED past the barrier so the pre-barrier vmcnt(0) drain never waits on HBM.
__launch_bounds__(1024, 4)
__global__ void tree_kernel(const float* __restrict__ x,
                            const float* __restrict__ leaf_w,
                            const float* __restrict__ leaf_b,
                            const float* __restrict__ conv_w,
                            const float* __restrict__ conv_b,
                            const float* __restrict__ bn_gamma,
                            const float* __restrict__ bn_beta,
                            const float* __restrict__ node_w,
                            unsigned short* __restrict__ pooledb,
                            const float* __restrict__ w1,
                            unsigned short* __restrict__ w1p) {
    extern __shared__ short smem[];
    short* buf0 = smem;
    short* buf1 = smem + SBUF;

    const int b   = blockIdx.x;
    const int tid = threadIdx.x;
    const int lane = tid & 63;
    const int wv   = tid >> 6;
    const int n    = lane & 15;
    const int g    = lane >> 4;

    if (tid < SROW) {
        buf0[1024 * SROW + tid] = 0;
        buf1[1024 * SROW + tid] = 0;
    }

    bf16x8 A1, A2;
#pragma unroll
    for (int j = 0; j < 8; ++j) {
        const int ci = (g & 1) * 8 + j;
        A1[j] = (short)f2b(conv_w[(n * C + ci) * 3 + (g >> 1)]);
        A2[j] = (g < 2) ? (short)f2b(conv_w[(n * C + ci) * 3 + 2]) : (short)0;
    }
    float sc4[4], bt4[4];
#pragma unroll
    for (int r = 0; r < 4; ++r) {
        const int co = g * 4 + r;
        float s = bn_gamma[co] / sqrtf(1.0f + 1e-5f);
        sc4[r] = s;
        bt4[r] = conv_b[co] * s + bn_beta[co];
    }

    // ---- leaf stage: 1 position per thread ----
    {
        const float xv = x[b * L + tid];
        const float nw = node_w[tid];
        const float4* lwa = (const float4*)(leaf_w + 16 * tid);
        const float4* lba = (const float4*)(leaf_b + 16 * tid);
        short* row = buf0 + tid * SROW;
#pragma unroll 1
        for (int q = 0; q < 4; ++q) {
            float4 wq = lwa[q], bq = lba[q];
            float v0 = (xv * wq.x + bq.x) * nw;
            float v1 = (xv * wq.y + bq.y) * nw;
            float v2 = (xv * wq.z + bq.z) * nw;
            float v3 = (xv * wq.w + bq.w) * nw;
            *(u64*)(row + 4 * q) =
                (u64)pk(v0, v1) | ((u64)pk(v2, v3) << 32);
            float p0 = fmaxf(v0, __shfl_xor(v0, 1));
            float p1 = fmaxf(v1, __shfl_xor(v1, 1));
            float p2 = fmaxf(v2, __shfl_xor(v2, 1));
            float p3 = fmaxf(v3, __shfl_xor(v3, 1));
            if (!(tid & 1)) {
                *(u64*)(pooledb + (long)b * FDIM + (tid >> 1) * 16 + 4 * q) =
                    (u64)pk(p0, p1) | ((u64)pk(p2, p3) << 32);
            }
        }
        __syncthreads();
    }

    // ---- 10 levels via MFMA; 4 tiles unrolled, stores deferred ----
    short* bin  = buf0;
    short* bout = buf1;
    int noff = L;
    for (int d = 0; d < 10; ++d) {
        const int sh = d + 1;
        const int mask = (1 << sh) - 1;

        u64 ps[4];
#pragma unroll
        for (int ti = 0; ti < 4; ++ti) {
            const int pos = (wv * 4 + ti) * 16 + n;
            const bool ok1 = (g >= 2) || ((pos & mask) != 0);
            const int r1 = ok1 ? (pos + (g >> 1) - 1) : 1024;
            bf16x8 B1 = *(const bf16x8*)(bin + r1 * SROW + (g & 1) * 8);
            const bool ok2 = ((pos & mask) != mask);
            const int r2 = ok2 ? (pos + 1) : 1024;
            bf16x8 B2 = *(const bf16x8*)(bin + r2 * SROW + (g & 1) * 8);

            f32x4 acc = {0.f, 0.f, 0.f, 0.f};
            acc = __builtin_amdgcn_mfma_f32_16x16x32_bf16(A1, B1, acc, 0, 0, 0);
            acc = __builtin_amdgcn_mfma_f32_16x16x32_bf16(A2, B2, acc, 0, 0, 0);

            const float nwv = node_w[noff + (pos >> sh)];
            float z[4];
#pragma unroll
            for (int r = 0; r < 4; ++r)
                z[r] = fmaxf(fmaf(sc4[r], acc[r], bt4[r]), 0.f) * nwv;

            *(u64*)(bout + pos * SROW + g * 4) =
                (u64)pk(z[0], z[1]) | ((u64)pk(z[2], z[3]) << 32);

            float pz0 = fmaxf(z[0], __shfl_xor(z[0], 1));
            float pz1 = fmaxf(z[1], __shfl_xor(z[1], 1));
            float pz2 = fmaxf(z[2], __shfl_xor(z[2], 1));
            float pz3 = fmaxf(z[3], __shfl_xor(z[3], 1));
            ps[ti] = (u64)pk(pz0, pz1) | ((u64)pk(pz2, pz3) << 32);
        }

        __syncthreads();   // LDS state complete; deferred stores issue AFTER

        if (!(n & 1)) {
#pragma unroll
            for (int ti = 0; ti < 4; ++ti) {
                const int pos = (wv * 4 + ti) * 16 + n;
                *(u64*)(pooledb + (long)b * FDIM + sh * 8192 + (pos >> 1) * 16 + g * 4) =
                    ps[ti];
            }
        }

        short* t = bin; bin = bout; bout = t;
        noff += (512 >> d);
    }

    __syncthreads();   // level-9 global stores may still be in flight (no LDS dep)

    // ---- tail: w1 f32 -> bf16 with feature permutation (grid-stride units) ----
    unsigned short* st = (unsigned short*)smem;   // [16][TROW] staging
    for (int unit = b; unit < 11 * H1; unit += BATCH) {
        const int lev = unit >> 7;
        const int nr  = unit & 127;
        const float* src = w1 + (long)nr * FDIM + lev * POOL;
#pragma unroll 2
        for (int i = tid; i < 2048; i += 1024) {       // i = c*128 + q (float4)
            const int c = i >> 7, q = i & 127;
            float4 v = *(const float4*)(src + (long)c * PCOLS + 4 * q);
            *(u64*)(st + c * TROW + 4 * q) =
                (u64)pk(v.x, v.y) | ((u64)pk(v.z, v.w) << 32);
        }
        __syncthreads();
#pragma unroll 2
        for (int i = tid; i < 2048; i += 1024) {       // i = pos2*4 + c4 (u64)
            const int pos2 = i >> 2, c4 = i & 3;
            unsigned short s0 = st[(c4 * 4 + 0) * TROW + pos2];
            unsigned short s1 = st[(c4 * 4 + 1) * TROW + pos2];
            unsigned short s2 = st[(c4 * 4 + 2) * TROW + pos2];
            unsigned short s3 = st[(c4 * 4 + 3) * TROW + pos2];
            *(u64*)(w1p + (long)nr * FDIM + lev * 8192 + pos2 * 16 + c4 * 4) =
                (u64)s0 | ((u64)s1 << 16) | ((u64)s2 << 32) | ((u64)s3 << 48);
        }
        __syncthreads();
    }
}

// ---------------- Kernel 2: fc1 via MFMA, single block per ks (pooled read ONCE) --
// grid = KS = 256; block 1024 thr = 16 waves; wave owns 16 rows x all 128 cols.
__launch_bounds__(1024, 4)
__global__ void fc1_mfma(const unsigned short* __restrict__ pooledb,
                         const unsigned short* __restrict__ w1b,
                         float* __restrict__ partial) {
    const int ks  = blockIdx.x;          // 0..255

    const int tid  = threadIdx.x;
    const int wv   = tid >> 6;           // 0..15
    const int lane = tid & 63;
    const int lrow = lane & 15;
    const int lk   = (lane >> 4) * 8;

    const int m0 = wv * 16;
    const int kb = ks * KCHUNK;

    const unsigned short* ap = pooledb + (long)(m0 + lrow) * FDIM + kb + lk;
    const unsigned short* bp = w1b + (long)lrow * FDIM + kb + lk;

    f32x4 acc[8];
#pragma unroll
    for (int ct = 0; ct < 8; ++ct) acc[ct] = (f32x4){0.f, 0.f, 0.f, 0.f};

#pragma unroll 2
    for (int kk = 0; kk < KCHUNK; kk += 32) {
        bf16x8 a = *(const bf16x8*)(ap + kk);
#pragma unroll
        for (int ct = 0; ct < 8; ++ct) {
            bf16x8 bv = *(const bf16x8*)(bp + (long)(ct * 16) * FDIM + kk);
            acc[ct] = __builtin_amdgcn_mfma_f32_16x16x32_bf16(a, bv, acc[ct], 0, 0, 0);
        }
    }

    // C/D: col = lane&15, row = (lane>>4)*4 + reg  [m89-verified]
    const int rbase = (lane >> 4) * 4;
    float* pp = partial + (long)ks * (BATCH * H1);
#pragma unroll
    for (int ct = 0; ct < 8; ++ct) {
        const int ccol = ct * 16 + (lane & 15);
#pragma unroll
        for (int r = 0; r < 4; ++r)
            pp[(long)(m0 + rbase + r) * H1 + ccol] = acc[ct][r];
    }
}

// ---------------- Kernel 3: parallel partial-reduce + fc1 bias/relu + fc2 + fc3 --
__launch_bounds__(1024)
__global__ void fc_tail(const float* __restrict__ partial,
                        const float* __restrict__ fc1_b,
                        const float* __restrict__ w2,
                        const float* __restrict__ b2,
                        const float* __restrict__ w3,
                        const float* __restrict__ b3,
                        float* __restrict__ out, int nkt) {
    __shared__ float red[8][H1];
    __shared__ float h1_s[H1];
    __shared__ float w2_s[H2 * 129];

    const int b = blockIdx.x;
    const int tid = threadIdx.x;
    const int t = tid & 127;      // h1 index
    const int q = tid >> 7;       // kt group 0..7

    const int per = nkt >> 3;     // 32
    float s = 0.f;
    const float* pb = partial + (long)(q * per) * (BATCH * H1) + b * H1 + t;
#pragma unroll 8
    for (int kt = 0; kt < per; ++kt)
        s += pb[(long)kt * (BATCH * H1)];
    red[q][t] = s;

    for (int i = tid; i < H2 * H1; i += 1024) {
        int j = i >> 7, k = i & 127;
        w2_s[j * 129 + k] = w2[i];
    }
    __syncthreads();

    if (tid < 128) {
        float ss = red[0][t] + red[1][t] + red[2][t] + red[3][t]
                 + red[4][t] + red[5][t] + red[6][t] + red[7][t];
        h1_s[t] = fmaxf(ss + fc1_b[t], 0.f);
    }
    __syncthreads();

    if (tid < 64) {
        float a2 = 0.f;
#pragma unroll 8
        for (int k = 0; k < H1; ++k) a2 = fmaf(h1_s[k], w2_s[tid * 129 + k], a2);
        float h2 = fmaxf(a2 + b2[tid], 0.f);
        float r = h2 * w3[tid];
#pragma unroll
        for (int off = 32; off > 0; off >>= 1) r += __shfl_down(r, off);
        if (tid == 0) out[b] = r + b3[0];
    }
}

extern "C" void kernel_launch(void* const* d_in, const int* in_sizes, int n_in,
                              void* d_out, int out_size, void* d_ws, size_t ws_size,
                              hipStream_t stream) {
    const float* x        = (const float*)d_in[0];
    const float* leaf_w   = (const float*)d_in[1];
    const float* leaf_b   = (const float*)d_in[2];
    const float* conv_w   = (const float*)d_in[3];
    const float* conv_b   = (const float*)d_in[4];
    const float* bn_gamma = (const float*)d_in[5];
    const float* bn_beta  = (const float*)d_in[6];
    const float* node_w   = (const float*)d_in[7];
    const float* fc1_w    = (const float*)d_in[8];
    const float* fc1_b    = (const float*)d_in[9];
    const float* fc2_w    = (const float*)d_in[10];
    const float* fc2_b    = (const float*)d_in[11];
    const float* fc3_w    = (const float*)d_in[12];
    const float* fc3_b    = (const float*)d_in[13];

    // ws: pooled bf16 (46.1MB) | w1p bf16 (23.1MB) | partial f32 (33.6MB) = 102.8MB
    unsigned short* pooledb = (unsigned short*)d_ws;
    unsigned short* w1p     = pooledb + (long)BATCH * FDIM;
    float*          partial = (float*)(w1p + (long)H1 * FDIM);

    (void)hipFuncSetAttribute((const void*)tree_kernel,
                        hipFuncAttributeMaxDynamicSharedMemorySize, TREE_LDS_BYTES);

    tree_kernel<<<BATCH, 1024, TREE_LDS_BYTES, stream>>>(
        x, leaf_w, leaf_b, conv_w, conv_b, bn_gamma, bn_beta, node_w, pooledb,
        fc1_w, w1p);

    fc1_mfma<<<KS, 1024, 0, stream>>>(pooledb, w1p, partial);

    fc_tail<<<BATCH, 1024, 0, stream>>>(partial, fc1_b, fc2_w, fc2_b, fc3_w, fc3_b,
                                        (float*)d_out, KS);
}

// Round 24
// 92.011 us; speedup vs baseline: 1.1625x; 1.1625x over previous
//
#include <hip/hip_runtime.h>
#include <hip/hip_bf16.h>

#define BATCH 256
#define L 1024
#define C 16
#define POOL 512
#define PCOLS 5632
#define FDIM 90112        // 11 levels * 8192
#define H1 128
#define H2 64

#define KS 256            // split-K factor for fc1 mfma GEMM
#define KCHUNK (FDIM / KS)   // 352

#define SROW 24                    // bf16 per state row (48B, 16B-aligned)
#define SBUF (1025 * SROW)         // +1 zero row
#define TREE_LDS_BYTES (2 * SBUF * 2)   // 98400 B

#define TROW 520                   // transpose-stage LDS row stride (shorts)

typedef float f32x4 __attribute__((ext_vector_type(4)));
typedef short bf16x8 __attribute__((ext_vector_type(8)));
typedef unsigned long long u64;

__device__ __forceinline__ unsigned short f2b(float f) {
    union { __hip_bfloat16 h; unsigned short u; } cv;
    cv.h = __float2bfloat16(f);          // RNE, hardware v_cvt
    return cv.u;
}
__device__ __forceinline__ unsigned int pk(float lo, float hi) {
    return (unsigned int)f2b(lo) | ((unsigned int)f2b(hi) << 16);
}

// ---------------- Kernel 1: tree via MFMA + fused w1 convert/permute ----------------
// pooled layout: f_new = level*8192 + pos2*16 + c   (w1 permuted to match)
// Levels 0..5 are WAVE-LOCAL (node zero-masks cover all wave-edge taps, since
// 64w is a multiple of L2<=64) -> no block barrier, only lgkmcnt(0).
// Barriers only after levels 5..8 (levels 6..9 read cross-wave).
__launch_bounds__(1024, 4)
__global__ void tree_kernel(const float* __restrict__ x,
                            const float* __restrict__ leaf_w,
                            const float* __restrict__ leaf_b,
                            const float* __restrict__ conv_w,
                            const float* __restrict__ conv_b,
                            const float* __restrict__ bn_gamma,
                            const float* __restrict__ bn_beta,
                            const float* __restrict__ node_w,
                            unsigned short* __restrict__ pooledb,
                            const float* __restrict__ w1,
                            unsigned short* __restrict__ w1p) {
    extern __shared__ short smem[];
    short* buf0 = smem;
    short* buf1 = smem + SBUF;

    const int b   = blockIdx.x;
    const int tid = threadIdx.x;
    const int lane = tid & 63;
    const int wv   = tid >> 6;
    const int n    = lane & 15;
    const int g    = lane >> 4;

    if (tid < SROW) {
        buf0[1024 * SROW + tid] = 0;
        buf1[1024 * SROW + tid] = 0;
    }

    bf16x8 A1, A2;
#pragma unroll
    for (int j = 0; j < 8; ++j) {
        const int ci = (g & 1) * 8 + j;
        A1[j] = (short)f2b(conv_w[(n * C + ci) * 3 + (g >> 1)]);
        A2[j] = (g < 2) ? (short)f2b(conv_w[(n * C + ci) * 3 + 2]) : (short)0;
    }
    float sc4[4], bt4[4];
#pragma unroll
    for (int r = 0; r < 4; ++r) {
        const int co = g * 4 + r;
        float s = bn_gamma[co] / sqrtf(1.0f + 1e-5f);
        sc4[r] = s;
        bt4[r] = conv_b[co] * s + bn_beta[co];
    }

    // ---- leaf stage: 1 position per thread ----
    {
        const float xv = x[b * L + tid];
        const float nw = node_w[tid];
        const float4* lwa = (const float4*)(leaf_w + 16 * tid);
        const float4* lba = (const float4*)(leaf_b + 16 * tid);
        short* row = buf0 + tid * SROW;
#pragma unroll 1
        for (int q = 0; q < 4; ++q) {
            float4 wq = lwa[q], bq = lba[q];
            float v0 = (xv * wq.x + bq.x) * nw;
            float v1 = (xv * wq.y + bq.y) * nw;
            float v2 = (xv * wq.z + bq.z) * nw;
            float v3 = (xv * wq.w + bq.w) * nw;
            *(u64*)(row + 4 * q) =
                (u64)pk(v0, v1) | ((u64)pk(v2, v3) << 32);
            float p0 = fmaxf(v0, __shfl_xor(v0, 1));
            float p1 = fmaxf(v1, __shfl_xor(v1, 1));
            float p2 = fmaxf(v2, __shfl_xor(v2, 1));
            float p3 = fmaxf(v3, __shfl_xor(v3, 1));
            if (!(tid & 1)) {
                *(u64*)(pooledb + (long)b * FDIM + (tid >> 1) * 16 + 4 * q) =
                    (u64)pk(p0, p1) | ((u64)pk(p2, p3) << 32);
            }
        }
        __syncthreads();   // zero rows + leaf state visible to all waves
    }

    // ---- 10 levels via MFMA ----
    short* bin  = buf0;
    short* bout = buf1;
    int noff = L;
    for (int d = 0; d < 10; ++d) {
        const int sh = d + 1;
        const int mask = (1 << sh) - 1;

#pragma unroll
        for (int ti = 0; ti < 4; ++ti) {
            const int pos = (wv * 4 + ti) * 16 + n;
            const bool ok1 = (g >= 2) || ((pos & mask) != 0);
            const int r1 = ok1 ? (pos + (g >> 1) - 1) : 1024;
            bf16x8 B1 = *(const bf16x8*)(bin + r1 * SROW + (g & 1) * 8);
            const bool ok2 = ((pos & mask) != mask);
            const int r2 = ok2 ? (pos + 1) : 1024;
            bf16x8 B2 = *(const bf16x8*)(bin + r2 * SROW + (g & 1) * 8);

            f32x4 acc = {0.f, 0.f, 0.f, 0.f};
            acc = __builtin_amdgcn_mfma_f32_16x16x32_bf16(A1, B1, acc, 0, 0, 0);
            acc = __builtin_amdgcn_mfma_f32_16x16x32_bf16(A2, B2, acc, 0, 0, 0);

            const float nwv = node_w[noff + (pos >> sh)];
            float z[4];
#pragma unroll
            for (int r = 0; r < 4; ++r)
                z[r] = fmaxf(fmaf(sc4[r], acc[r], bt4[r]), 0.f) * nwv;

            if (d < 9) {
                *(u64*)(bout + pos * SROW + g * 4) =
                    (u64)pk(z[0], z[1]) | ((u64)pk(z[2], z[3]) << 32);
            }

            float pz0 = fmaxf(z[0], __shfl_xor(z[0], 1));
            float pz1 = fmaxf(z[1], __shfl_xor(z[1], 1));
            float pz2 = fmaxf(z[2], __shfl_xor(z[2], 1));
            float pz3 = fmaxf(z[3], __shfl_xor(z[3], 1));
            if (!(n & 1)) {
                *(u64*)(pooledb + (long)b * FDIM + sh * 8192 + (pos >> 1) * 16 + g * 4) =
                    (u64)pk(pz0, pz1) | ((u64)pk(pz2, pz3) << 32);
            }
        }

        if (d >= 5 && d < 9) {
            __syncthreads();                 // next level reads cross-wave
        } else {
            // wave-local level: only require this wave's LDS ops complete
            asm volatile("s_waitcnt lgkmcnt(0)" ::: "memory");
        }

        short* t = bin; bin = bout; bout = t;
        noff += (512 >> d);
    }

    __syncthreads();   // protect smem reuse below; drains remaining stores' deps

    // ---- tail: w1 f32 -> bf16 with feature permutation (grid-stride units) ----
    unsigned short* st = (unsigned short*)smem;   // [16][TROW] staging
    for (int unit = b; unit < 11 * H1; unit += BATCH) {
        const int lev = unit >> 7;
        const int nr  = unit & 127;
        const float* src = w1 + (long)nr * FDIM + lev * POOL;
#pragma unroll 2
        for (int i = tid; i < 2048; i += 1024) {       // i = c*128 + q (float4)
            const int c = i >> 7, q = i & 127;
            float4 v = *(const float4*)(src + (long)c * PCOLS + 4 * q);
            *(u64*)(st + c * TROW + 4 * q) =
                (u64)pk(v.x, v.y) | ((u64)pk(v.z, v.w) << 32);
        }
        __syncthreads();
#pragma unroll 2
        for (int i = tid; i < 2048; i += 1024) {       // i = pos2*4 + c4 (u64)
            const int pos2 = i >> 2, c4 = i & 3;
            unsigned short s0 = st[(c4 * 4 + 0) * TROW + pos2];
            unsigned short s1 = st[(c4 * 4 + 1) * TROW + pos2];
            unsigned short s2 = st[(c4 * 4 + 2) * TROW + pos2];
            unsigned short s3 = st[(c4 * 4 + 3) * TROW + pos2];
            *(u64*)(w1p + (long)nr * FDIM + lev * 8192 + pos2 * 16 + c4 * 4) =
                (u64)s0 | ((u64)s1 << 16) | ((u64)s2 << 32) | ((u64)s3 << 48);
        }
        __syncthreads();
    }
}

// ---------------- Kernel 2: fc1 via MFMA, M=256/block for B-reuse (R22-proven) ----
__launch_bounds__(512, 2)
__global__ void fc1_mfma(const unsigned short* __restrict__ pooledb,
                         const unsigned short* __restrict__ w1b,
                         float* __restrict__ partial) {
    const int bid = blockIdx.x;
    const int ks  = bid & (KS - 1);      // 0..255
    const int bn  = bid >> 8;            // 0..1

    const int tid  = threadIdx.x;
    const int wv   = tid >> 6;           // 0..7
    const int lane = tid & 63;
    const int lrow = lane & 15;
    const int lk   = (lane >> 4) * 8;

    const int m0 = wv * 32;
    const int n0 = bn * 64;
    const int kb = ks * KCHUNK;

    const unsigned short* ap0 = pooledb + (long)(m0 + lrow) * FDIM + kb + lk;
    const unsigned short* ap1 = ap0 + (long)16 * FDIM;
    const unsigned short* bp  = w1b + (long)(n0 + lrow) * FDIM + kb + lk;

    f32x4 acc00 = {0,0,0,0}, acc01 = {0,0,0,0}, acc02 = {0,0,0,0}, acc03 = {0,0,0,0};
    f32x4 acc10 = {0,0,0,0}, acc11 = {0,0,0,0}, acc12 = {0,0,0,0}, acc13 = {0,0,0,0};

#pragma unroll 2
    for (int kk = 0; kk < KCHUNK; kk += 32) {
        bf16x8 a0 = *(const bf16x8*)(ap0 + kk);
        bf16x8 a1 = *(const bf16x8*)(ap1 + kk);
        bf16x8 b0 = *(const bf16x8*)(bp + kk);
        bf16x8 b1 = *(const bf16x8*)(bp + (long)16 * FDIM + kk);
        bf16x8 b2 = *(const bf16x8*)(bp + (long)32 * FDIM + kk);
        bf16x8 b3 = *(const bf16x8*)(bp + (long)48 * FDIM + kk);
        acc00 = __builtin_amdgcn_mfma_f32_16x16x32_bf16(a0, b0, acc00, 0, 0, 0);
        acc01 = __builtin_amdgcn_mfma_f32_16x16x32_bf16(a0, b1, acc01, 0, 0, 0);
        acc02 = __builtin_amdgcn_mfma_f32_16x16x32_bf16(a0, b2, acc02, 0, 0, 0);
        acc03 = __builtin_amdgcn_mfma_f32_16x16x32_bf16(a0, b3, acc03, 0, 0, 0);
        acc10 = __builtin_amdgcn_mfma_f32_16x16x32_bf16(a1, b0, acc10, 0, 0, 0);
        acc11 = __builtin_amdgcn_mfma_f32_16x16x32_bf16(a1, b1, acc11, 0, 0, 0);
        acc12 = __builtin_amdgcn_mfma_f32_16x16x32_bf16(a1, b2, acc12, 0, 0, 0);
        acc13 = __builtin_amdgcn_mfma_f32_16x16x32_bf16(a1, b3, acc13, 0, 0, 0);
    }

    const int rbase = (lane >> 4) * 4;
    const int ccol  = n0 + (lane & 15);
    float* pp = partial + (long)ks * (BATCH * H1);
#pragma unroll
    for (int r = 0; r < 4; ++r) {
        const int row0 = m0 + rbase + r;
        pp[(long)row0 * H1 + ccol]      = acc00[r];
        pp[(long)row0 * H1 + ccol + 16] = acc01[r];
        pp[(long)row0 * H1 + ccol + 32] = acc02[r];
        pp[(long)row0 * H1 + ccol + 48] = acc03[r];
        const int row1 = row0 + 16;
        pp[(long)row1 * H1 + ccol]      = acc10[r];
        pp[(long)row1 * H1 + ccol + 16] = acc11[r];
        pp[(long)row1 * H1 + ccol + 32] = acc12[r];
        pp[(long)row1 * H1 + ccol + 48] = acc13[r];
    }
}

// ---------------- Kernel 3: parallel partial-reduce + fc1 bias/relu + fc2 + fc3 --
__launch_bounds__(1024)
__global__ void fc_tail(const float* __restrict__ partial,
                        const float* __restrict__ fc1_b,
                        const float* __restrict__ w2,
                        const float* __restrict__ b2,
                        const float* __restrict__ w3,
                        const float* __restrict__ b3,
                        float* __restrict__ out, int nkt) {
    __shared__ float red[8][H1];
    __shared__ float h1_s[H1];
    __shared__ float w2_s[H2 * 129];

    const int b = blockIdx.x;
    const int tid = threadIdx.x;
    const int t = tid & 127;      // h1 index
    const int q = tid >> 7;       // kt group 0..7

    const int per = nkt >> 3;     // 32
    float s = 0.f;
    const float* pb = partial + (long)(q * per) * (BATCH * H1) + b * H1 + t;
#pragma unroll 8
    for (int kt = 0; kt < per; ++kt)
        s += pb[(long)kt * (BATCH * H1)];
    red[q][t] = s;

    for (int i = tid; i < H2 * H1; i += 1024) {
        int j = i >> 7, k = i & 127;
        w2_s[j * 129 + k] = w2[i];
    }
    __syncthreads();

    if (tid < 128) {
        float ss = red[0][t] + red[1][t] + red[2][t] + red[3][t]
                 + red[4][t] + red[5][t] + red[6][t] + red[7][t];
        h1_s[t] = fmaxf(ss + fc1_b[t], 0.f);
    }
    __syncthreads();

    if (tid < 64) {
        float a2 = 0.f;
#pragma unroll 8
        for (int k = 0; k < H1; ++k) a2 = fmaf(h1_s[k], w2_s[tid * 129 + k], a2);
        float h2 = fmaxf(a2 + b2[tid], 0.f);
        float r = h2 * w3[tid];
#pragma unroll
        for (int off = 32; off > 0; off >>= 1) r += __shfl_down(r, off);
        if (tid == 0) out[b] = r + b3[0];
    }
}

extern "C" void kernel_launch(void* const* d_in, const int* in_sizes, int n_in,
                              void* d_out, int out_size, void* d_ws, size_t ws_size,
                              hipStream_t stream) {
    const float* x        = (const float*)d_in[0];
    const float* leaf_w   = (const float*)d_in[1];
    const float* leaf_b   = (const float*)d_in[2];
    const float* conv_w   = (const float*)d_in[3];
    const float* conv_b   = (const float*)d_in[4];
    const float* bn_gamma = (const float*)d_in[5];
    const float* bn_beta  = (const float*)d_in[6];
    const float* node_w   = (const float*)d_in[7];
    const float* fc1_w    = (const float*)d_in[8];
    const float* fc1_b    = (const float*)d_in[9];
    const float* fc2_w    = (const float*)d_in[10];
    const float* fc2_b    = (const float*)d_in[11];
    const float* fc3_w    = (const float*)d_in[12];
    const float* fc3_b    = (const float*)d_in[13];

    // ws: pooled bf16 (46.1MB) | w1p bf16 (23.1MB) | partial f32 (33.6MB) = 102.8MB
    unsigned short* pooledb = (unsigned short*)d_ws;
    unsigned short* w1p     = pooledb + (long)BATCH * FDIM;
    float*          partial = (float*)(w1p + (long)H1 * FDIM);

    (void)hipFuncSetAttribute((const void*)tree_kernel,
                        hipFuncAttributeMaxDynamicSharedMemorySize, TREE_LDS_BYTES);

    tree_kernel<<<BATCH, 1024, TREE_LDS_BYTES, stream>>>(
        x, leaf_w, leaf_b, conv_w, conv_b, bn_gamma, bn_beta, node_w, pooledb,
        fc1_w, w1p);

    fc1_mfma<<<2 * KS, 512, 0, stream>>>(pooledb, w1p, partial);

    fc_tail<<<BATCH, 1024, 0, stream>>>(partial, fc1_b, fc2_w, fc2_b, fc3_w, fc3_b,
                                        (float*)d_out, KS);
}